// Round 5
// baseline (4031.380 us; speedup 1.0000x reference)
//
#include <hip/hip_runtime.h>
#include <cstddef>

// WITRAN 2D PSGMU encoder, MI355X — v9: the recurrence factorizes over the
// batch index. h_col's roll is (r,b)->(r+1,b): b never mixes, so the 768-slot
// scan = 32 INDEPENDENT 24-slot x 71-step problems. One block per b-group =>
// the whole 71-step recurrence runs in ONE dispatch with only __syncthreads()
// between steps (no cross-block sync at all — v6's failure mode is void).
//   - h state lives entirely in LDS: ping-pong As[2][32][552] fp16 (70.7 KB).
//     ZERO global h traffic for the entire run.
//   - wave w owns k-slices kt=w and kt=w+8: GEMM (2 m-tiles x 6 gate groups
//     x 17 kc) then updates its k-slice WAVE-LOCALLY from its accumulators
//     (D layout: col=lane&15=gate col, row=quad*4+reg). No Gt buffer, no
//     mid-step barrier. One barrier per step (ping-pong removes all hazards).
//   - W fragments stream from per-XCD L2 (1.67 MB/block/step; 4 blocks/XCD
//     share one hot copy; nothing ever invalidates it).
// Numerics identical to v8 (fp16 MFMA 16x16x32, fp32 gates/update, fp16 h
// carry): absmax expected bit-equal at 9.77e-4.

namespace {
constexpr int H_   = 256;
constexpr int R_   = 24;
constexpr int LOR_ = 48;
constexpr int L_   = 71;
constexpr int KT_  = 544;
constexpr int AST_ = 552;   // LDS A stride (elems): 1104 B/row -> 2-way banks on b128
}

typedef __attribute__((ext_vector_type(8))) _Float16     f16x8;
typedef __attribute__((ext_vector_type(4))) float        f32x4;
typedef __attribute__((ext_vector_type(4))) unsigned int u32x4;

__device__ __forceinline__ float fsig(float x)  { return 1.f / (1.f + __expf(-x)); }
__device__ __forceinline__ float ftanhf(float x){ float e = __expf(2.f * x); return 1.f - 2.f / (e + 1.f); }

// ---------------------------------------------------------------------------
// Fused prep: Wfrag (verified fragment layout) + x shift/convert.
// Wfrag[((kc*96 + lt)*64 + lane)*8 + j8]; lt=kt*6+g; col j=g*256+kt*16+kl
// xall layout: [s][b][r][c]  (per-block contiguous 24x32 tile per step)
// ---------------------------------------------------------------------------
__global__ __launch_bounds__(256) void prep_all(const float* __restrict__ W,
                                                const float* __restrict__ inp,
                                                _Float16* __restrict__ Wfrag,
                                                _Float16* __restrict__ xall) {
    const int bx = blockIdx.x;
    const int t  = threadIdx.x;
    if (bx < 3264) {                                 // W -> fragment fp16
        int o = bx * 256 + t;                        // < 835,584
        int j8   = o & 7;
        int lane = (o >> 3) & 63;
        int rest = o >> 9;
        int lt   = rest % 96;
        int kc   = rest / 96;                        // < 17
        int n0 = lane & 15, quad = lane >> 4;
        int lg  = lt * 16 + n0;
        int kt  = lg / 96;
        int rem = lg % 96;
        int g  = rem >> 4, kl = rem & 15;
        int j  = g * 256 + kt * 16 + kl;
        int kg = kc * 32 + quad * 8 + j8;
        Wfrag[o] = (_Float16)W[j * KT_ + kg];
    } else {                                         // shifted x, [s][b][r][c]
        int o = (bx - 3264) * 256 + t;               // < 1,744,896
        int c  = o & 31;
        int q  = o >> 5;                             // (s*32+b)*24 + r
        int r  = q % 24;
        int q2 = q / 24;                             // s*32 + b
        int b  = q2 & 31;
        int s  = q2 >> 5;
        int l  = s - r;
        float v = 0.f;
        if (l >= 0 && l < LOR_) v = inp[((b * LOR_ + l) * R_ + r) * 32 + c];
        xall[o] = (_Float16)v;
    }
}

// ---------------------------------------------------------------------------
// The whole recurrence: 32 blocks (one per batch b), 512 thr = 8 waves.
// ---------------------------------------------------------------------------
__global__ __launch_bounds__(512, 2) void steps_all(
    const _Float16* __restrict__ Wfrag,
    const _Float16* __restrict__ xall,
    const float* __restrict__ Bp,
    float* __restrict__ out0, float* __restrict__ out1, float* __restrict__ out2)
{
    __shared__ __align__(16) _Float16 As[2][32 * AST_];  // rows 24..31 = zero pad

    const int t    = threadIdx.x;
    const int wv   = t >> 6;                   // 0..7
    const int lane = t & 63;
    const int kl   = lane & 15;
    const int quad = lane >> 4;
    const int b    = blockIdx.x;

    // ---- init: zero both buffers, stage x(0) into buf0 ----------------------
    {
        u32x4 z = (u32x4){0u, 0u, 0u, 0u};
        u32x4* p = (u32x4*)(void*)&As[0][0];
        for (int i = t; i < 4416; i += 512) p[i] = z;   // 70,656 B
    }
    __syncthreads();
    if (t < 96) {
        int row = t >> 2, col = (t & 3) * 8;
        *(f16x8*)(void*)&As[0][row * AST_ + 512 + col] =
            *(const f16x8*)(const void*)(xall + ((size_t)b * 24 + row) * 32 + col);
    }

    // ---- per-wave constants: bias for both owned k-slices -------------------
    float bpA[6], bpB[6];
#pragma unroll
    for (int g = 0; g < 6; ++g) {
        bpA[g] = Bp[g * 256 + wv * 16 + kl];
        bpB[g] = Bp[g * 256 + (wv + 8) * 16 + kl];
    }
    __syncthreads();

    for (int s = 0; s < L_; ++s) {
        const _Float16* Ac = &As[s & 1][0];
        _Float16*       An = &As[(s & 1) ^ 1][0];

        auto pass = [&](const int kt, const float (&bp)[6]) {
            f32x4 acc[6][2];
#pragma unroll
            for (int g = 0; g < 6; ++g) {
                acc[g][0] = (f32x4){0.f, 0.f, 0.f, 0.f};
                acc[g][1] = (f32x4){0.f, 0.f, 0.f, 0.f};
            }
            const _Float16* wb = Wfrag + ((size_t)(kt * 6) * 64 + lane) * 8;
#pragma unroll
            for (int kc = 0; kc < 17; ++kc) {
                f16x8 bb[6];
#pragma unroll
                for (int g = 0; g < 6; ++g)
                    bb[g] = *(const f16x8*)(const void*)(
                        wb + (size_t)kc * (96 * 512) + g * 512);
                f16x8 a0 = *(const f16x8*)(const void*)&Ac[kl * AST_ + kc * 32 + quad * 8];
                f16x8 a1 = *(const f16x8*)(const void*)&Ac[(16 + kl) * AST_ + kc * 32 + quad * 8];
#pragma unroll
                for (int g = 0; g < 6; ++g) {
                    acc[g][0] = __builtin_amdgcn_mfma_f32_16x16x32_f16(a0, bb[g], acc[g][0], 0, 0, 0);
                    acc[g][1] = __builtin_amdgcn_mfma_f32_16x16x32_f16(a1, bb[g], acc[g][1], 0, 0, 0);
                }
            }
            // ---- wave-local update of k-slice kt --------------------------
            const int k = kt * 16 + kl;
#pragma unroll
            for (int mt = 0; mt < 2; ++mt) {
                if (mt == 1 && quad >= 2) continue;   // rows 24..31 = pad
#pragma unroll
                for (int reg = 0; reg < 4; ++reg) {
                    const int m = mt * 16 + quad * 4 + reg;   // slot r = m
                    const bool useb = (m <= s) && (s < R_);
                    float g0 = acc[0][mt][reg] + (useb ? bp[0] : 0.f);
                    float g1 = acc[1][mt][reg] + (useb ? bp[1] : 0.f);
                    float g2 = acc[2][mt][reg] + (useb ? bp[2] : 0.f);
                    float g3 = acc[3][mt][reg] + (useb ? bp[3] : 0.f);
                    float g4 = acc[4][mt][reg] + (useb ? bp[4] : 0.f);
                    float g5 = acc[5][mt][reg] + (useb ? bp[5] : 0.f);
                    float ur = fsig(g0), orr = fsig(g1);
                    float uc = fsig(g2), oc  = fsig(g3);
                    float ir = ftanhf(g4), ic = ftanhf(g5);
                    float hro = (float)Ac[m * AST_ + k];
                    float hco = (float)Ac[m * AST_ + 256 + k];
                    float hrv = ftanhf((1.f - ur) * hro + ur * ir) * orr;
                    float hcv = ftanhf((1.f - uc) * hco + uc * ic) * oc;
                    An[m * AST_ + k] = (_Float16)hrv;
                    int mw = m + 1; if (mw == R_) mw = 0;     // h_col roll (r+1, wrap)
                    An[mw * AST_ + 256 + k] = (_Float16)hcv;
                    float* o0 = out0 + ((size_t)(m * 32 + b) * L_ + s) * 512;
                    __builtin_nontemporal_store(hrv, o0 + k);
                    __builtin_nontemporal_store(hcv, o0 + 256 + k);
                    if (s >= LOR_ - 1 && m == s - (LOR_ - 1))
                        __builtin_nontemporal_store(hrv, out2 + ((size_t)b * R_ + m) * H_ + k);
                    if (m == R_ - 1 && s >= R_ - 1)
                        __builtin_nontemporal_store(hcv, out1 + ((size_t)b * LOR_ + (s - (R_ - 1))) * H_ + k);
                }
            }
        };

        pass(wv,     bpA);
        pass(wv + 8, bpB);

        // ---- stage x(s+1) into the next buffer ---------------------------
        if (s + 1 < L_ && t < 96) {
            int row = t >> 2, col = (t & 3) * 8;
            *(f16x8*)(void*)&An[row * AST_ + 512 + col] =
                *(const f16x8*)(const void*)(
                    xall + ((size_t)((s + 1) * 32 + b) * 24 + row) * 32 + col);
        }
        __syncthreads();
    }
}

// ---------------------------------------------------------------------------
extern "C" void kernel_launch(void* const* d_in, const int* in_sizes, int n_in,
                              void* d_out, int out_size, void* d_ws, size_t ws_size,
                              hipStream_t stream) {
    const float* inp = (const float*)d_in[0];
    const float* W   = (const float*)d_in[1];
    const float* Bp  = (const float*)d_in[2];

    float* out0 = (float*)d_out;
    float* out1 = out0 + (size_t)768 * L_ * 512;
    float* out2 = out1 + (size_t)32 * LOR_ * H_;

    char* ws = (char*)d_ws;
    _Float16* Wfrag = (_Float16*)(ws);                 // 1,671,168 B
    _Float16* xall  = (_Float16*)(ws + 1671168);       // 3,489,792 B

    prep_all<<<10080, 256, 0, stream>>>(W, inp, Wfrag, xall);
    steps_all<<<32, 512, 0, stream>>>(Wfrag, xall, Bp, out0, out1, out2);
}

// Round 6
// 3965.070 us; speedup vs baseline: 1.0167x; 1.0167x over previous
//
#include <hip/hip_runtime.h>
#include <cstddef>

// WITRAN 2D PSGMU encoder, MI355X — v10: persistent batch-factorized kernel
// (v9 structure: 32 independent per-b recurrences, h entirely in LDS
// ping-pong, ONE dispatch, one barrier/step) with the latency fix:
//   v9 failed at 55.7us/step because launch_bounds(512,2) capped VGPR at 128
//   and 2 waves/SIMD gave no latency cover -> the 6-fragment W load group
//   serialized (~200 exposed L2/LLC misses/step, MfmaUtil 1.2%).
//   v10: 1024 thr = 16 waves = 4 waves/SIMD; each wave owns ONE kt slice
//   (6 loads + 12 MFMA per kc, all loads independent). 4-way TLP bounds the
//   step at ~1.6us/SIMD even if every W load misses to HBM. VGPR ~110 < 128.
//   Output stores switched NT->plain so L2 merges partial 64B segments.
// Numerics identical to v8/v9 (fp16 MFMA 16x16x32, fp32 gates, fp16 carry):
// absmax must stay bit-equal at 9.766e-4.

namespace {
constexpr int H_   = 256;
constexpr int R_   = 24;
constexpr int LOR_ = 48;
constexpr int L_   = 71;
constexpr int KT_  = 544;
constexpr int AST_ = 552;   // LDS A stride (elems)
}

typedef __attribute__((ext_vector_type(8))) _Float16     f16x8;
typedef __attribute__((ext_vector_type(4))) float        f32x4;
typedef __attribute__((ext_vector_type(4))) unsigned int u32x4;

__device__ __forceinline__ float fsig(float x)  { return 1.f / (1.f + __expf(-x)); }
__device__ __forceinline__ float ftanhf(float x){ float e = __expf(2.f * x); return 1.f - 2.f / (e + 1.f); }

// ---------------------------------------------------------------------------
// Fused prep: Wfrag (verified fragment layout) + x shift/convert.
// Wfrag[((kc*96 + lt)*64 + lane)*8 + j8]; lt=kt*6+g; col j=g*256+kt*16+kl
// xall layout: [s][b][r][c]
// ---------------------------------------------------------------------------
__global__ __launch_bounds__(256) void prep_all(const float* __restrict__ W,
                                                const float* __restrict__ inp,
                                                _Float16* __restrict__ Wfrag,
                                                _Float16* __restrict__ xall) {
    const int bx = blockIdx.x;
    const int t  = threadIdx.x;
    if (bx < 3264) {                                 // W -> fragment fp16
        int o = bx * 256 + t;                        // < 835,584
        int j8   = o & 7;
        int lane = (o >> 3) & 63;
        int rest = o >> 9;
        int lt   = rest % 96;
        int kc   = rest / 96;                        // < 17
        int n0 = lane & 15, quad = lane >> 4;
        int lg  = lt * 16 + n0;
        int kt  = lg / 96;
        int rem = lg % 96;
        int g  = rem >> 4, kl = rem & 15;
        int j  = g * 256 + kt * 16 + kl;
        int kg = kc * 32 + quad * 8 + j8;
        Wfrag[o] = (_Float16)W[j * KT_ + kg];
    } else {                                         // shifted x, [s][b][r][c]
        int o = (bx - 3264) * 256 + t;               // < 1,744,896
        int c  = o & 31;
        int q  = o >> 5;                             // (s*32+b)*24 + r
        int r  = q % 24;
        int q2 = q / 24;                             // s*32 + b
        int b  = q2 & 31;
        int s  = q2 >> 5;
        int l  = s - r;
        float v = 0.f;
        if (l >= 0 && l < LOR_) v = inp[((b * LOR_ + l) * R_ + r) * 32 + c];
        xall[o] = (_Float16)v;
    }
}

// ---------------------------------------------------------------------------
// The whole recurrence: 32 blocks (one per batch b), 1024 thr = 16 waves,
// wave wv owns k-slice kt = wv. 4 waves/SIMD.
// ---------------------------------------------------------------------------
__global__ __launch_bounds__(1024, 4) void steps_all(
    const _Float16* __restrict__ Wfrag,
    const _Float16* __restrict__ xall,
    const float* __restrict__ Bp,
    float* __restrict__ out0, float* __restrict__ out1, float* __restrict__ out2)
{
    __shared__ __align__(16) _Float16 As[2][32 * AST_];  // rows 24..31 = zero pad

    const int t    = threadIdx.x;
    const int wv   = t >> 6;                   // 0..15 = kt
    const int lane = t & 63;
    const int kl   = lane & 15;
    const int quad = lane >> 4;
    const int b    = blockIdx.x;

    // ---- init: zero both buffers, then stage x(0) into buf0 -----------------
    {
        u32x4 z = (u32x4){0u, 0u, 0u, 0u};
        u32x4* p = (u32x4*)(void*)&As[0][0];
        for (int i = t; i < 4416; i += 1024) p[i] = z;   // both buffers, 70,656 B
    }
    __syncthreads();
    if (t < 96) {
        int row = t >> 2, col = (t & 3) * 8;
        *(f16x8*)(void*)&As[0][row * AST_ + 512 + col] =
            *(const f16x8*)(const void*)(xall + ((size_t)b * 24 + row) * 32 + col);
    }

    float bp[6];
#pragma unroll
    for (int g = 0; g < 6; ++g)
        bp[g] = Bp[g * 256 + wv * 16 + kl];
    __syncthreads();

    const _Float16* wb = Wfrag + ((size_t)(wv * 6) * 64 + lane) * 8;
    const int k = wv * 16 + kl;

    for (int s = 0; s < L_; ++s) {
        const _Float16* Ac = &As[s & 1][0];
        _Float16*       An = &As[(s & 1) ^ 1][0];

        // ---- GEMM: 17 kc x {6 W loads, 2 LDS reads, 12 MFMA} ----------------
        f32x4 acc[6][2];
#pragma unroll
        for (int g = 0; g < 6; ++g) {
            acc[g][0] = (f32x4){0.f, 0.f, 0.f, 0.f};
            acc[g][1] = (f32x4){0.f, 0.f, 0.f, 0.f};
        }
#pragma unroll
        for (int kc = 0; kc < 17; ++kc) {
            f16x8 w[6];
#pragma unroll
            for (int g = 0; g < 6; ++g)
                w[g] = *(const f16x8*)(const void*)(
                    wb + (size_t)kc * (96 * 512) + g * 512);
            f16x8 a0 = *(const f16x8*)(const void*)&Ac[kl * AST_ + kc * 32 + quad * 8];
            f16x8 a1 = *(const f16x8*)(const void*)&Ac[(16 + kl) * AST_ + kc * 32 + quad * 8];
#pragma unroll
            for (int g = 0; g < 6; ++g) {
                acc[g][0] = __builtin_amdgcn_mfma_f32_16x16x32_f16(a0, w[g], acc[g][0], 0, 0, 0);
                acc[g][1] = __builtin_amdgcn_mfma_f32_16x16x32_f16(a1, w[g], acc[g][1], 0, 0, 0);
            }
        }

        // ---- wave-local update of k-slice kt=wv -----------------------------
        // D layout: col = lane&15 (gate col), row = quad*4 + reg (m)
#pragma unroll
        for (int mt = 0; mt < 2; ++mt) {
            if (mt == 1 && quad >= 2) continue;   // rows 24..31 = pad
#pragma unroll
            for (int reg = 0; reg < 4; ++reg) {
                const int m = mt * 16 + quad * 4 + reg;   // slot r = m
                const bool useb = (m <= s) && (s < R_);
                float g0 = acc[0][mt][reg] + (useb ? bp[0] : 0.f);
                float g1 = acc[1][mt][reg] + (useb ? bp[1] : 0.f);
                float g2 = acc[2][mt][reg] + (useb ? bp[2] : 0.f);
                float g3 = acc[3][mt][reg] + (useb ? bp[3] : 0.f);
                float g4 = acc[4][mt][reg] + (useb ? bp[4] : 0.f);
                float g5 = acc[5][mt][reg] + (useb ? bp[5] : 0.f);
                float ur = fsig(g0), orr = fsig(g1);
                float uc = fsig(g2), oc  = fsig(g3);
                float ir = ftanhf(g4), ic = ftanhf(g5);
                float hro = (float)Ac[m * AST_ + k];
                float hco = (float)Ac[m * AST_ + 256 + k];
                float hrv = ftanhf((1.f - ur) * hro + ur * ir) * orr;
                float hcv = ftanhf((1.f - uc) * hco + uc * ic) * oc;
                An[m * AST_ + k] = (_Float16)hrv;
                int mw = m + 1; if (mw == R_) mw = 0;     // h_col roll (r+1, wrap)
                An[mw * AST_ + 256 + k] = (_Float16)hcv;
                float* o0 = out0 + ((size_t)(m * 32 + b) * L_ + s) * 512;
                o0[k]       = hrv;
                o0[256 + k] = hcv;
                if (s >= LOR_ - 1 && m == s - (LOR_ - 1))
                    out2[((size_t)b * R_ + m) * H_ + k] = hrv;
                if (m == R_ - 1 && s >= R_ - 1)
                    out1[((size_t)b * LOR_ + (s - (R_ - 1))) * H_ + k] = hcv;
            }
        }

        // ---- stage x(s+1) into the next buffer ------------------------------
        if (s + 1 < L_ && t < 96) {
            int row = t >> 2, col = (t & 3) * 8;
            *(f16x8*)(void*)&An[row * AST_ + 512 + col] =
                *(const f16x8*)(const void*)(
                    xall + ((size_t)((s + 1) * 32 + b) * 24 + row) * 32 + col);
        }
        __syncthreads();
    }
}

// ---------------------------------------------------------------------------
extern "C" void kernel_launch(void* const* d_in, const int* in_sizes, int n_in,
                              void* d_out, int out_size, void* d_ws, size_t ws_size,
                              hipStream_t stream) {
    const float* inp = (const float*)d_in[0];
    const float* W   = (const float*)d_in[1];
    const float* Bp  = (const float*)d_in[2];

    float* out0 = (float*)d_out;
    float* out1 = out0 + (size_t)768 * L_ * 512;
    float* out2 = out1 + (size_t)32 * LOR_ * H_;

    char* ws = (char*)d_ws;
    _Float16* Wfrag = (_Float16*)(ws);                 // 1,671,168 B
    _Float16* xall  = (_Float16*)(ws + 1671168);       // 3,489,792 B

    prep_all<<<10080, 256, 0, stream>>>(W, inp, Wfrag, xall);
    steps_all<<<32, 1024, 0, stream>>>(Wfrag, xall, Bp, out0, out1, out2);
}

// Round 8
// 640.090 us; speedup vs baseline: 6.2981x; 6.1946x over previous
//
#include <hip/hip_runtime.h>
#include <cstddef>

// WITRAN 2D PSGMU encoder, MI355X — v12: v11 with the double-swizzle bug
// fixed. Rule-21 pattern done RIGHT:
//   - global h buffer: LINEAR layout (writer = v8's plain packed-u32 store)
//   - gl_lds stage: per-lane PRE-SWIZZLED global source addr
//       src = row*1024 + ((lane*16) ^ ((row&7)<<4)), linear LDS dest
//     => LDS holds value(row,c) at byte (2c)^((row&7)<<4)  (swizzled tile)
//   - all LDS reads (GEMM fragments + update h_old) apply the same XOR.
//   v11 ALSO swizzled the global layout, so the two XORs cancelled: LDS was
//   linear while reads swizzled -> permuted operands, absmax 0.155.
// Bank math: rows stride 1024 B (bank-aliased); XOR by (row&7)<<4 spreads 8
// rows over the 128 B bank period -> ~2-way (free) vs 16-way linear.
// Coalescing: each gl_lds instruction's 64 lanes cover one 1024 B row,
// permuted within it -> still one coalesced segment.
// Base structure = v8 (629 us): 256 blocks = 16mc x 16kt, 384 thr, W
// reg-prefetch, fp16 h carry, launch-per-step (persistent routes refuted:
// v6 20.4us/step, v9/v10 per-CU W-BW floor 10.9us/step).
// Numerics identical to v8: absmax must be exactly 9.766e-4.

namespace {
constexpr int H_   = 256;
constexpr int R_   = 24;
constexpr int LOR_ = 48;
constexpr int L_   = 71;
constexpr int N_   = 768;
constexpr int KH_  = 512;
constexpr int KT_  = 544;
constexpr int XST_ = 40;    // Xs stride (halves): 80 B
}

typedef __attribute__((ext_vector_type(8))) _Float16       f16x8;
typedef __attribute__((ext_vector_type(4))) float          f32x4;
typedef __attribute__((ext_vector_type(2))) float          f32x2;

typedef __attribute__((address_space(3))) void       lds_void_t;
typedef const __attribute__((address_space(1))) void gbl_void_t;

__device__ __forceinline__ float fsig(float x)  { return 1.f / (1.f + __expf(-x)); }
__device__ __forceinline__ float ftanhf(float x){ float e = __expf(2.f * x); return 1.f - 2.f / (e + 1.f); }

// ---------------------------------------------------------------------------
// Fused prep: Wfrag build + x shift/convert + hb0 zero-init.
// Wfrag[((kc*96 + lt)*64 + lane)*8 + j8]; lt=kt*6+g; col j=g*256+kt*16+kl
// ---------------------------------------------------------------------------
__global__ __launch_bounds__(256) void prep_all(const float* __restrict__ W,
                                                const float* __restrict__ inp,
                                                _Float16* __restrict__ Wfrag,
                                                _Float16* __restrict__ xall,
                                                unsigned long long* __restrict__ zb) {
    const int bx = blockIdx.x;
    const int t  = threadIdx.x;
    if (bx < 3264) {                                 // W -> fragment fp16
        int o = bx * 256 + t;                        // < 835,584
        int j8   = o & 7;
        int lane = (o >> 3) & 63;
        int rest = o >> 9;
        int lt   = rest % 96;
        int kc   = rest / 96;                        // < 17
        int n0 = lane & 15, quad = lane >> 4;
        int lg  = lt * 16 + n0;
        int kt  = lg / 96;
        int rem = lg % 96;
        int g  = rem >> 4, kl = rem & 15;
        int j  = g * 256 + kt * 16 + kl;
        int kg = kc * 32 + quad * 8 + j8;
        Wfrag[o] = (_Float16)W[j * KT_ + kg];
    } else if (bx < 10080) {                         // shifted x, [s][n][c]
        int o = (bx - 3264) * 256 + t;               // < 1,744,896
        int c = o & 31;
        int n = (o >> 5) % N_;
        int s = (o >> 5) / N_;
        int r = n >> 5, b = n & 31;
        int l = s - r;
        float v = 0.f;
        if (l >= 0 && l < LOR_) v = inp[((b * LOR_ + l) * R_ + r) * 32 + c];
        xall[o] = (_Float16)v;
    } else {                                         // zero hb0 (98,304 u64)
        zb[(bx - 10080) * 256 + t] = 0ull;
    }
}

// ---------------------------------------------------------------------------
// One step. 256 blocks: kt = bx&15, mc = bx>>4 (rows [mc*48, +48)).
// 6 waves, wave wv = gate group g. 1 block/CU. Global h layout: LINEAR.
// ---------------------------------------------------------------------------
__global__ __launch_bounds__(384, 2) void step_k(
    const _Float16* __restrict__ Wfrag,
    const _Float16* __restrict__ xall,
    const _Float16* __restrict__ hbc,
    _Float16*       __restrict__ hbn,
    const float* __restrict__ Bp,
    float* __restrict__ out0, float* __restrict__ out1, float* __restrict__ out2,
    int s)
{
    __shared__ __align__(16) _Float16 Hs[48 * 512];   // swizzled tile (gl_lds dest)
    __shared__ __align__(16) _Float16 Xs[48 * XST_];
    __shared__ float Gt[48][98];

    const int t    = threadIdx.x;
    const int wv   = t >> 6;                   // 0..5 = gate group g
    const int lane = t & 63;
    const int n0   = lane & 15;
    const int quad = lane >> 4;
    const int kt   = blockIdx.x & 15;
    const int mc   = blockIdx.x >> 4;

    // ---- async stage h: 48 x global_load_lds_dwordx4 (1 KB rows) ------------
    // linear global + pre-swizzled SOURCE addr -> swizzled LDS content
    {
        const char* hsrc = (const char*)hbc + (size_t)mc * 48 * 1024;
#pragma unroll
        for (int it = 0; it < 8; ++it) {
            int q   = it * 384 + t;            // < 3072 granules; q&63 == lane
            int row = q >> 6;
            int g16 = q & 63;
            int srz = row * 1024 + ((g16 * 16) ^ ((row & 7) << 4));
            __builtin_amdgcn_global_load_lds(
                (gbl_void_t*)(hsrc + srz),
                (lds_void_t*)((char*)&Hs[0] + (q & ~63) * 16),
                16, 0, 0);
        }
    }

    // ---- W prefetch: all 17 fragments (overlaps the async stage) ------------
    f16x8 bfr[17];
#pragma unroll
    for (int kc = 0; kc < 17; ++kc)
        bfr[kc] = *(const f16x8*)(const void*)(
            Wfrag + ((size_t)(kc * 96 + kt * 6 + wv) * 64 + lane) * 8);

    // ---- early Bp loads (only steps that use the bias) ----------------------
    const int mm = t >> 3;                     // update row (0..47)
    const int kp = (t & 7) * 2;
    const int n  = mc * 48 + mm;
    const int k  = kt * 16 + kp;
    f32x2 bp[6];
    if (s < R_) {
#pragma unroll
        for (int g = 0; g < 6; ++g)
            bp[g] = *(const f32x2*)(const void*)(Bp + g * 256 + k);
    }

    // ---- stage x (small, plain ds_write) ------------------------------------
    if (t < 192) {
        int row = t >> 2;
        int col = (t & 3) * 8;
        *(f16x8*)(void*)(&Xs[row * XST_ + col]) =
            *(const f16x8*)(const void*)((const unsigned short*)xall +
                                         (size_t)(s * N_ + mc * 48 + row) * 32 + col);
    }
    __syncthreads();

    // ---- GEMM: wave = gate g, 3 m-tiles x 16 gate cols, W from registers ----
    f32x4 acc[3];
#pragma unroll
    for (int mt = 0; mt < 3; ++mt) acc[mt] = (f32x4){0.f, 0.f, 0.f, 0.f};

    const int swzl = (n0 & 7) << 4;            // lane-constant read swizzle
#pragma unroll
    for (int kc = 0; kc < 17; ++kc) {
        f16x8 a[3];
        if (kc < 16) {
#pragma unroll
            for (int mt = 0; mt < 3; ++mt)
                a[mt] = *(const f16x8*)(const void*)(
                    (const char*)&Hs[0] + (mt * 16 + n0) * 1024 +
                    ((kc * 64 + quad * 16) ^ swzl));
        } else {
#pragma unroll
            for (int mt = 0; mt < 3; ++mt)
                a[mt] = *(const f16x8*)(const void*)(
                    &Xs[(mt * 16 + n0) * XST_ + quad * 8]);
        }
#pragma unroll
        for (int mt = 0; mt < 3; ++mt)
            acc[mt] = __builtin_amdgcn_mfma_f32_16x16x32_f16(a[mt], bfr[kc], acc[mt], 0, 0, 0);
    }

    // D layout: col = lane&15 (gate col), row = quad*4 + reg (m)
#pragma unroll
    for (int mt = 0; mt < 3; ++mt)
#pragma unroll
        for (int reg = 0; reg < 4; ++reg)
            Gt[mt * 16 + quad * 4 + reg][wv * 16 + n0] = acc[mt][reg];

    __syncthreads();

    // ---- fused update: 48m x 16k, thread = 1 m-row x 2 k --------------------
    {
        const int r  = n >> 5, b = n & 31;
        const bool useb = (r <= s) && (s < R_);

        f32x2 gv[6];
#pragma unroll
        for (int g = 0; g < 6; ++g) {
            f32x2 v = *(const f32x2*)(const void*)&Gt[mm][g * 16 + kp];
            gv[g] = useb ? (v + bp[g]) : v;
        }

        // h_old from the swizzled LDS tile
        const int swzu = (mm & 7) << 4;
        union { unsigned int u; _Float16 h[2]; } hru, hcu;
        hru.u = *(const unsigned int*)(const void*)(
            (const char*)&Hs[0] + mm * 1024 + ((2 * k) ^ swzu));
        hcu.u = *(const unsigned int*)(const void*)(
            (const char*)&Hs[0] + mm * 1024 + ((512 + 2 * k) ^ swzu));
        f32x2 hro = { (float)hru.h[0], (float)hru.h[1] };
        f32x2 hco = { (float)hcu.h[0], (float)hcu.h[1] };

        f32x2 hrv, hcv;
#pragma unroll
        for (int j = 0; j < 2; ++j) {
            float ur = fsig(gv[0][j]);
            float oR = fsig(gv[1][j]);
            float uc = fsig(gv[2][j]);
            float oc = fsig(gv[3][j]);
            float ir = ftanhf(gv[4][j]);
            float ic = ftanhf(gv[5][j]);
            hrv[j] = ftanhf((1.f - ur) * hro[j] + ur * ir) * oR;
            hcv[j] = ftanhf((1.f - uc) * hco[j] + uc * ic) * oc;
        }

        // trace output (write-only: non-temporal, keep L2 clean for W/h)
        float* o0 = out0 + ((size_t)n * L_ + s) * 512;
        __builtin_nontemporal_store(hrv, (f32x2*)(void*)(o0 + k));
        __builtin_nontemporal_store(hcv, (f32x2*)(void*)(o0 + 256 + k));

        int n2 = n + 32; if (n2 >= N_) n2 -= N_;

        // LINEAR global h stores (v8 layout — swizzle lives only in LDS)
        union { _Float16 h[2]; unsigned int u; } pr, pc;
        pr.h[0] = (_Float16)hrv[0]; pr.h[1] = (_Float16)hrv[1];
        pc.h[0] = (_Float16)hcv[0]; pc.h[1] = (_Float16)hcv[1];
        *(unsigned int*)(void*)(hbn + (size_t)n  * KH_ + k)       = pr.u;
        *(unsigned int*)(void*)(hbn + (size_t)n2 * KH_ + 256 + k) = pc.u;

        if (s >= LOR_ - 1 && r == s - (LOR_ - 1))
            __builtin_nontemporal_store(hrv, (f32x2*)(void*)(out2 + (size_t)(b * R_ + r) * H_ + k));
        if (r == R_ - 1 && s >= R_ - 1)
            __builtin_nontemporal_store(hcv, (f32x2*)(void*)(out1 + (size_t)(b * LOR_ + (s - (R_ - 1))) * H_ + k));
    }
}

// ---------------------------------------------------------------------------
extern "C" void kernel_launch(void* const* d_in, const int* in_sizes, int n_in,
                              void* d_out, int out_size, void* d_ws, size_t ws_size,
                              hipStream_t stream) {
    const float* inp = (const float*)d_in[0];
    const float* W   = (const float*)d_in[1];
    const float* Bp  = (const float*)d_in[2];

    float* out0 = (float*)d_out;
    float* out1 = out0 + (size_t)N_ * L_ * 512;
    float* out2 = out1 + (size_t)32 * LOR_ * H_;

    char* ws = (char*)d_ws;
    _Float16* Wfrag = (_Float16*)(ws);                 // 1,671,168 B
    _Float16* xall  = (_Float16*)(ws + 1671168);       // 3,489,792 B
    _Float16* hb0   = (_Float16*)(ws + 5160960);       //   786,432 B
    _Float16* hb1   = (_Float16*)(ws + 5947392);       //   786,432 B

    prep_all<<<10464, 256, 0, stream>>>(W, inp, Wfrag, xall,
                                        (unsigned long long*)hb0);

    for (int s = 0; s < L_; ++s) {
        const _Float16* hbc = (s & 1) ? hb1 : hb0;
        _Float16*       hbn = (s & 1) ? hb0 : hb1;
        step_k<<<256, 384, 0, stream>>>(Wfrag, xall, hbc, hbn,
                                        Bp, out0, out1, out2, s);
    }
}

// Round 9
// 616.593 us; speedup vs baseline: 6.5382x; 1.0381x over previous
//
#include <hip/hip_runtime.h>
#include <cstddef>

// WITRAN 2D PSGMU encoder, MI355X — v13: v8 base (best measured: 629us;
// 256 blocks = 16mc x 16kt, 384 thr, W reg-prefetch, fp16 h carry from LDS,
// launch-per-step) + triangular dead-work elimination:
//   Slots with r > s are EXACTLY zero (h=0, x=0, mask=0 -> tanh(0)*sig(0)=0),
//   and the harness pre-zeroes the output buffer. So step s only launches
//   chunks covering groups 0..min(s,23): grid = ceil(2*(min(s,23)+1)/3)*16
//   blocks (16 at s=0, full 256 from s>=23). Requires BOTH ping-pong h
//   buffers zeroed in prep (unlaunched chunks never write; stale data in the
//   off-parity buffer would corrupt a chunk's first active step).
//   Boundary: chunk nmc-1 writes h_col into chunk nmc's rows = exactly the
//   data chunk nmc needs when it activates; its h_row rows stay zero.
// Also: x-tile (17th kc) loaded directly into registers per wave (3 x f16x8,
// prefetched pre-barrier) — removes the Xs LDS stage entirely.
// Counter-refuted structures (do not revisit): v6 flag-sync 20.4us/step;
// v7 2-block/CU (+33% padded MFMA, wash); v9/v10 persistent batch-factorized
// (per-CU W stream >=10.9us/step); v12 gl_lds swizzled stage (640us, wash).
// Numerics identical to v8: absmax must be exactly 9.766e-4.

namespace {
constexpr int H_   = 256;
constexpr int R_   = 24;
constexpr int LOR_ = 48;
constexpr int L_   = 71;
constexpr int N_   = 768;
constexpr int KH_  = 512;
constexpr int KT_  = 544;
constexpr int AST_ = 552;   // LDS A stride (elems)
}

typedef __attribute__((ext_vector_type(8))) _Float16       f16x8;
typedef __attribute__((ext_vector_type(8))) unsigned short u16x8;
typedef __attribute__((ext_vector_type(4))) float          f32x4;
typedef __attribute__((ext_vector_type(2))) float          f32x2;

__device__ __forceinline__ float fsig(float x)  { return 1.f / (1.f + __expf(-x)); }
__device__ __forceinline__ float ftanhf(float x){ float e = __expf(2.f * x); return 1.f - 2.f / (e + 1.f); }

// ---------------------------------------------------------------------------
// Fused prep: Wfrag build + x shift/convert + BOTH h buffers zeroed.
// Wfrag[((kc*96 + lt)*64 + lane)*8 + j8]; lt=kt*6+g; col j=g*256+kt*16+kl
// ---------------------------------------------------------------------------
__global__ __launch_bounds__(256) void prep_all(const float* __restrict__ W,
                                                const float* __restrict__ inp,
                                                _Float16* __restrict__ Wfrag,
                                                _Float16* __restrict__ xall,
                                                unsigned long long* __restrict__ zb) {
    const int bx = blockIdx.x;
    const int t  = threadIdx.x;
    if (bx < 3264) {                                 // W -> fragment fp16
        int o = bx * 256 + t;                        // < 835,584
        int j8   = o & 7;
        int lane = (o >> 3) & 63;
        int rest = o >> 9;
        int lt   = rest % 96;
        int kc   = rest / 96;                        // < 17
        int n0 = lane & 15, quad = lane >> 4;
        int lg  = lt * 16 + n0;
        int kt  = lg / 96;
        int rem = lg % 96;
        int g  = rem >> 4, kl = rem & 15;
        int j  = g * 256 + kt * 16 + kl;
        int kg = kc * 32 + quad * 8 + j8;
        Wfrag[o] = (_Float16)W[j * KT_ + kg];
    } else if (bx < 10080) {                         // shifted x, [s][n][c]
        int o = (bx - 3264) * 256 + t;               // < 1,744,896
        int c = o & 31;
        int n = (o >> 5) % N_;
        int s = (o >> 5) / N_;
        int r = n >> 5, b = n & 31;
        int l = s - r;
        float v = 0.f;
        if (l >= 0 && l < LOR_) v = inp[((b * LOR_ + l) * R_ + r) * 32 + c];
        xall[o] = (_Float16)v;
    } else {                                         // zero hb0+hb1 (196,608 u64)
        zb[(bx - 10080) * 256 + t] = 0ull;
    }
}

// ---------------------------------------------------------------------------
// One step. Grid = nmc*16 blocks: kt = bx&15, mc = bx>>4 (rows [mc*48, +48)).
// 6 waves, wave wv = gate group g. 1 block/CU.
// ---------------------------------------------------------------------------
__global__ __launch_bounds__(384, 2) void step_k(
    const _Float16* __restrict__ Wfrag,
    const _Float16* __restrict__ xall,
    const _Float16* __restrict__ hbc,
    _Float16*       __restrict__ hbn,
    const float* __restrict__ Bp,
    float* __restrict__ out0, float* __restrict__ out1, float* __restrict__ out2,
    int s)
{
    __shared__ unsigned short As[48 * AST_];   // h tile: 48 x 512 (stride 552)
    __shared__ float Gt[48][98];               // gate tile 48m x 96l

    const int t    = threadIdx.x;
    const int wv   = t >> 6;                   // 0..5 = gate group g
    const int lane = t & 63;
    const int n0   = lane & 15;
    const int quad = lane >> 4;
    const int kt   = blockIdx.x & 15;
    const int mc   = blockIdx.x >> 4;

    // ---- W prefetch: all 17 fragments issued first --------------------------
    f16x8 bfr[17];
#pragma unroll
    for (int kc = 0; kc < 17; ++kc)
        bfr[kc] = *(const f16x8*)(const void*)(
            Wfrag + ((size_t)(kc * 96 + kt * 6 + wv) * 64 + lane) * 8);

    // ---- x fragments direct to registers (17th kc A-operand) ----------------
    f16x8 xf[3];
#pragma unroll
    for (int mt = 0; mt < 3; ++mt)
        xf[mt] = *(const f16x8*)(const void*)(
            xall + ((size_t)(s * N_ + mc * 48 + mt * 16 + n0)) * 32 + quad * 8);

    // ---- early Bp loads (only steps that use the bias) ----------------------
    const int mm = t >> 3;                     // update row (0..47)
    const int kp = (t & 7) * 2;
    const int n  = mc * 48 + mm;
    const int k  = kt * 16 + kp;
    f32x2 bp[6];
    if (s < R_) {
#pragma unroll
        for (int g = 0; g < 6; ++g)
            bp[g] = *(const f32x2*)(const void*)(Bp + g * 256 + k);
    }

    // ---- stage h (48x512) into LDS ------------------------------------------
#pragma unroll
    for (int it = 0; it < 8; ++it) {
        int q   = it * 384 + t;                // < 3072
        int row = q >> 6;
        int col = (q & 63) * 8;
        *(u16x8*)(void*)(&As[row * AST_ + col]) =
            *(const u16x8*)(const void*)((const unsigned short*)hbc +
                                         (size_t)(mc * 48 + row) * KH_ + col);
    }
    __syncthreads();

    // ---- GEMM: wave = gate g, 3 m-tiles x 16 gate cols, W+x from registers --
    f32x4 acc[3];
#pragma unroll
    for (int mt = 0; mt < 3; ++mt) acc[mt] = (f32x4){0.f, 0.f, 0.f, 0.f};

#pragma unroll
    for (int kc = 0; kc < 16; ++kc) {
        f16x8 a[3];
#pragma unroll
        for (int mt = 0; mt < 3; ++mt)
            a[mt] = *(const f16x8*)(const void*)(
                &As[(mt * 16 + n0) * AST_ + kc * 32 + quad * 8]);
#pragma unroll
        for (int mt = 0; mt < 3; ++mt)
            acc[mt] = __builtin_amdgcn_mfma_f32_16x16x32_f16(a[mt], bfr[kc], acc[mt], 0, 0, 0);
    }
#pragma unroll
    for (int mt = 0; mt < 3; ++mt)
        acc[mt] = __builtin_amdgcn_mfma_f32_16x16x32_f16(xf[mt], bfr[16], acc[mt], 0, 0, 0);

    // D layout: col = lane&15 (gate col), row = quad*4 + reg (m)
#pragma unroll
    for (int mt = 0; mt < 3; ++mt)
#pragma unroll
        for (int reg = 0; reg < 4; ++reg)
            Gt[mt * 16 + quad * 4 + reg][wv * 16 + n0] = acc[mt][reg];

    __syncthreads();

    // ---- fused update: 48m x 16k, thread = 1 m-row x 2 k --------------------
    {
        const int r  = n >> 5, b = n & 31;
        const bool useb = (r <= s) && (s < R_);

        f32x2 gv[6];
#pragma unroll
        for (int g = 0; g < 6; ++g) {
            f32x2 v = *(const f32x2*)(const void*)&Gt[mm][g * 16 + kp];
            gv[g] = useb ? (v + bp[g]) : v;
        }

        // h_old straight from the staged LDS tile (fp16 carry)
        const _Float16* hrow = (const _Float16*)(const void*)&As[mm * AST_ + k];
        const _Float16* hcol = (const _Float16*)(const void*)&As[mm * AST_ + 256 + k];
        f32x2 hro = { (float)hrow[0], (float)hrow[1] };
        f32x2 hco = { (float)hcol[0], (float)hcol[1] };

        f32x2 hrv, hcv;
#pragma unroll
        for (int j = 0; j < 2; ++j) {
            float ur = fsig(gv[0][j]);
            float oR = fsig(gv[1][j]);
            float uc = fsig(gv[2][j]);
            float oc = fsig(gv[3][j]);
            float ir = ftanhf(gv[4][j]);
            float ic = ftanhf(gv[5][j]);
            hrv[j] = ftanhf((1.f - ur) * hro[j] + ur * ir) * oR;
            hcv[j] = ftanhf((1.f - uc) * hco[j] + uc * ic) * oc;
        }

        // trace output (write-only: non-temporal, keep L2 clean for W/h)
        float* o0 = out0 + ((size_t)n * L_ + s) * 512;
        __builtin_nontemporal_store(hrv, (f32x2*)(void*)(o0 + k));
        __builtin_nontemporal_store(hcv, (f32x2*)(void*)(o0 + 256 + k));

        int n2 = n + 32; if (n2 >= N_) n2 -= N_;

        union { _Float16 h[2]; unsigned int u; } pr, pc;
        pr.h[0] = (_Float16)hrv[0]; pr.h[1] = (_Float16)hrv[1];
        pc.h[0] = (_Float16)hcv[0]; pc.h[1] = (_Float16)hcv[1];
        *(unsigned int*)(void*)(hbn + (size_t)n  * KH_ + k)       = pr.u;
        *(unsigned int*)(void*)(hbn + (size_t)n2 * KH_ + 256 + k) = pc.u;

        if (s >= LOR_ - 1 && r == s - (LOR_ - 1))
            __builtin_nontemporal_store(hrv, (f32x2*)(void*)(out2 + (size_t)(b * R_ + r) * H_ + k));
        if (r == R_ - 1 && s >= R_ - 1)
            __builtin_nontemporal_store(hcv, (f32x2*)(void*)(out1 + (size_t)(b * LOR_ + (s - (R_ - 1))) * H_ + k));
    }
}

// ---------------------------------------------------------------------------
extern "C" void kernel_launch(void* const* d_in, const int* in_sizes, int n_in,
                              void* d_out, int out_size, void* d_ws, size_t ws_size,
                              hipStream_t stream) {
    const float* inp = (const float*)d_in[0];
    const float* W   = (const float*)d_in[1];
    const float* Bp  = (const float*)d_in[2];

    float* out0 = (float*)d_out;
    float* out1 = out0 + (size_t)N_ * L_ * 512;
    float* out2 = out1 + (size_t)32 * LOR_ * H_;

    char* ws = (char*)d_ws;
    _Float16* Wfrag = (_Float16*)(ws);                 // 1,671,168 B
    _Float16* xall  = (_Float16*)(ws + 1671168);       // 3,489,792 B
    _Float16* hb0   = (_Float16*)(ws + 5160960);       //   786,432 B
    _Float16* hb1   = (_Float16*)(ws + 5947392);       //   786,432 B (contiguous with hb0)

    prep_all<<<10848, 256, 0, stream>>>(W, inp, Wfrag, xall,
                                        (unsigned long long*)hb0);

    for (int s = 0; s < L_; ++s) {
        const _Float16* hbc = (s & 1) ? hb1 : hb0;
        _Float16*       hbn = (s & 1) ? hb0 : hb1;
        int act = (s < 23 ? s : 23) + 1;               // active r-groups
        int nmc = (32 * act + 47) / 48;                // active 48-row chunks
        step_k<<<nmc * 16, 384, 0, stream>>>(Wfrag, xall, hbc, hbn,
                                             Bp, out0, out1, out2, s);
    }
}

// Round 10
// 579.122 us; speedup vs baseline: 6.9612x; 1.0647x over previous
//
#include <hip/hip_runtime.h>
#include <cstddef>

// WITRAN 2D PSGMU encoder, MI355X — v14: v13 base (616us: launch-per-step,
// triangle grid, W reg-prefetch, x-in-regs, fp16 h carry) + two levers:
//  1. SPLIT-K / 12 waves (768 thr, 3 waves/SIMD): waves 0-5 = gate g, kc 0-8;
//     waves 6-11 = gate g, kc 9-16 (incl x). Halves each wave's serial kc
//     chain, doubles latency cover (GEMM phase was ds_read/dep-stall bound
//     at 1.5 waves/SIMD, ~10% in-phase MFMA util). Partials in Gt[2],
//     summed in the update (fp32; summation-order drift expected <=2e-3).
//  2. XCD-LOCAL bid swizzle on full-grid steps (s>=22): all 16 kt-blocks of
//     chunk mc on XCD mc&7 (bid = (((mc>>3)<<4)|kt)*8 + (mc&7)) -> h rows
//     written+read within one XCD L2 (stage ~600 -> ~250cy). Identity map on
//     triangle steps (decode requires contiguous full grid).
// Rejected on paper: 2-step fusion (needs full-K per block -> re-streams all
// of W per CU = v9/v10's 10.9us/step per-CU BW floor).
// Counter-refuted: v6 flag-sync, v7 2-blk/CU, v9/v10 persistent, v12 gl_lds.

namespace {
constexpr int H_   = 256;
constexpr int R_   = 24;
constexpr int LOR_ = 48;
constexpr int L_   = 71;
constexpr int N_   = 768;
constexpr int KH_  = 512;
constexpr int KT_  = 544;
constexpr int AST_ = 552;   // LDS h-tile stride (elems)
}

typedef __attribute__((ext_vector_type(8))) _Float16       f16x8;
typedef __attribute__((ext_vector_type(8))) unsigned short u16x8;
typedef __attribute__((ext_vector_type(4))) float          f32x4;

__device__ __forceinline__ float fsig(float x)  { return 1.f / (1.f + __expf(-x)); }
__device__ __forceinline__ float ftanhf(float x){ float e = __expf(2.f * x); return 1.f - 2.f / (e + 1.f); }

// ---------------------------------------------------------------------------
// Fused prep: Wfrag build + x shift/convert + BOTH h buffers zeroed.
// Wfrag[((kc*96 + lt)*64 + lane)*8 + j8]; lt=kt*6+g; col j=g*256+kt*16+kl
// ---------------------------------------------------------------------------
__global__ __launch_bounds__(256) void prep_all(const float* __restrict__ W,
                                                const float* __restrict__ inp,
                                                _Float16* __restrict__ Wfrag,
                                                _Float16* __restrict__ xall,
                                                unsigned long long* __restrict__ zb) {
    const int bx = blockIdx.x;
    const int t  = threadIdx.x;
    if (bx < 3264) {                                 // W -> fragment fp16
        int o = bx * 256 + t;                        // < 835,584
        int j8   = o & 7;
        int lane = (o >> 3) & 63;
        int rest = o >> 9;
        int lt   = rest % 96;
        int kc   = rest / 96;                        // < 17
        int n0 = lane & 15, quad = lane >> 4;
        int lg  = lt * 16 + n0;
        int kt  = lg / 96;
        int rem = lg % 96;
        int g  = rem >> 4, kl = rem & 15;
        int j  = g * 256 + kt * 16 + kl;
        int kg = kc * 32 + quad * 8 + j8;
        Wfrag[o] = (_Float16)W[j * KT_ + kg];
    } else if (bx < 10080) {                         // shifted x, [s][n][c]
        int o = (bx - 3264) * 256 + t;               // < 1,744,896
        int c = o & 31;
        int n = (o >> 5) % N_;
        int s = (o >> 5) / N_;
        int r = n >> 5, b = n & 31;
        int l = s - r;
        float v = 0.f;
        if (l >= 0 && l < LOR_) v = inp[((b * LOR_ + l) * R_ + r) * 32 + c];
        xall[o] = (_Float16)v;
    } else {                                         // zero hb0+hb1 (196,608 u64)
        zb[(bx - 10080) * 256 + t] = 0ull;
    }
}

// ---------------------------------------------------------------------------
// One step. Grid = nmc*16 blocks. 768 thr = 12 waves, 3 waves/SIMD.
// Waves 0-5: gate g=wv, kc 0-8.  Waves 6-11: gate g=wv-6, kc 9-16 (incl x).
// ---------------------------------------------------------------------------
__global__ __launch_bounds__(768, 3) void step_k(
    const _Float16* __restrict__ Wfrag,
    const _Float16* __restrict__ xall,
    const _Float16* __restrict__ hbc,
    _Float16*       __restrict__ hbn,
    const float* __restrict__ Bp,
    float* __restrict__ out0, float* __restrict__ out1, float* __restrict__ out2,
    int s)
{
    __shared__ unsigned short As[48 * AST_];   // h tile 48x512 (stride 552)
    __shared__ float Gt[2][48][98];            // split-K partial gates

    const int t    = threadIdx.x;
    const int wv   = t >> 6;                   // 0..11
    const int lane = t & 63;
    const int n0   = lane & 15;
    const int quad = lane >> 4;

    // block decode: XCD-local swizzle on full-grid steps (s>=22)
    int kt, mc;
    if (s >= 22) {
        int x = blockIdx.x & 7, q = blockIdx.x >> 3;
        kt = q & 15; mc = ((q >> 4) << 3) | x;
    } else {
        kt = blockIdx.x & 15; mc = blockIdx.x >> 4;
    }

    const bool hi = (wv >= 6);
    const int  g  = hi ? wv - 6 : wv;

    // ---- W prefetch (this wave's kc range) ----------------------------------
    f16x8 bfr[9];
    f16x8 xf[3];
    if (!hi) {
#pragma unroll
        for (int i = 0; i < 9; ++i)
            bfr[i] = *(const f16x8*)(const void*)(
                Wfrag + ((size_t)(i * 96 + kt * 6 + g) * 64 + lane) * 8);
    } else {
#pragma unroll
        for (int i = 0; i < 8; ++i)
            bfr[i] = *(const f16x8*)(const void*)(
                Wfrag + ((size_t)((9 + i) * 96 + kt * 6 + g) * 64 + lane) * 8);
#pragma unroll
        for (int mt = 0; mt < 3; ++mt)
            xf[mt] = *(const f16x8*)(const void*)(
                xall + ((size_t)(s * N_ + mc * 48 + mt * 16 + n0)) * 32 + quad * 8);
    }

    // ---- early Bp loads -----------------------------------------------------
    const int mm = t >> 4;                     // update row (0..47)
    const int kp = t & 15;
    const int n  = mc * 48 + mm;
    const int k  = kt * 16 + kp;
    float bp[6];
    if (s < R_) {
#pragma unroll
        for (int gg = 0; gg < 6; ++gg)
            bp[gg] = Bp[gg * 256 + k];
    }

    // ---- stage h (48x512) into LDS ------------------------------------------
#pragma unroll
    for (int it = 0; it < 4; ++it) {
        int q   = it * 768 + t;                // < 3072
        int row = q >> 6;
        int col = (q & 63) * 8;
        *(u16x8*)(void*)(&As[row * AST_ + col]) =
            *(const u16x8*)(const void*)((const unsigned short*)hbc +
                                         (size_t)(mc * 48 + row) * KH_ + col);
    }
    __syncthreads();

    // ---- GEMM: split-K halves -----------------------------------------------
    f32x4 acc[3];
#pragma unroll
    for (int mt = 0; mt < 3; ++mt) acc[mt] = (f32x4){0.f, 0.f, 0.f, 0.f};

    if (!hi) {
#pragma unroll
        for (int i = 0; i < 9; ++i) {
            f16x8 a[3];
#pragma unroll
            for (int mt = 0; mt < 3; ++mt)
                a[mt] = *(const f16x8*)(const void*)(
                    &As[(mt * 16 + n0) * AST_ + i * 32 + quad * 8]);
#pragma unroll
            for (int mt = 0; mt < 3; ++mt)
                acc[mt] = __builtin_amdgcn_mfma_f32_16x16x32_f16(a[mt], bfr[i], acc[mt], 0, 0, 0);
        }
    } else {
#pragma unroll
        for (int i = 0; i < 7; ++i) {
            f16x8 a[3];
#pragma unroll
            for (int mt = 0; mt < 3; ++mt)
                a[mt] = *(const f16x8*)(const void*)(
                    &As[(mt * 16 + n0) * AST_ + (9 + i) * 32 + quad * 8]);
#pragma unroll
            for (int mt = 0; mt < 3; ++mt)
                acc[mt] = __builtin_amdgcn_mfma_f32_16x16x32_f16(a[mt], bfr[i], acc[mt], 0, 0, 0);
        }
#pragma unroll
        for (int mt = 0; mt < 3; ++mt)
            acc[mt] = __builtin_amdgcn_mfma_f32_16x16x32_f16(xf[mt], bfr[7], acc[mt], 0, 0, 0);
    }

    // D layout: col = lane&15 (gate col), row = quad*4 + reg (m)
    {
        float (*gt)[98] = Gt[hi ? 1 : 0];
#pragma unroll
        for (int mt = 0; mt < 3; ++mt)
#pragma unroll
            for (int reg = 0; reg < 4; ++reg)
                gt[mt * 16 + quad * 4 + reg][g * 16 + n0] = acc[mt][reg];
    }
    __syncthreads();

    // ---- fused update: thread = 1 m-row x 1 k -------------------------------
    {
        const int r  = n >> 5, b = n & 31;
        const bool useb = (r <= s) && (s < R_);

        float gv[6];
#pragma unroll
        for (int gg = 0; gg < 6; ++gg) {
            float v = Gt[0][mm][gg * 16 + kp] + Gt[1][mm][gg * 16 + kp];
            gv[gg] = useb ? (v + bp[gg]) : v;
        }

        float hro = (float)*(const _Float16*)(const void*)&As[mm * AST_ + k];
        float hco = (float)*(const _Float16*)(const void*)&As[mm * AST_ + 256 + k];

        float ur = fsig(gv[0]), oR = fsig(gv[1]);
        float uc = fsig(gv[2]), oc = fsig(gv[3]);
        float ir = ftanhf(gv[4]), ic = ftanhf(gv[5]);
        float hrv = ftanhf((1.f - ur) * hro + ur * ir) * oR;
        float hcv = ftanhf((1.f - uc) * hco + uc * ic) * oc;

        float* o0 = out0 + ((size_t)n * L_ + s) * 512;
        __builtin_nontemporal_store(hrv, o0 + k);
        __builtin_nontemporal_store(hcv, o0 + 256 + k);

        int n2 = n + 32; if (n2 >= N_) n2 -= N_;
        hbn[(size_t)n  * KH_ + k]       = (_Float16)hrv;
        hbn[(size_t)n2 * KH_ + 256 + k] = (_Float16)hcv;

        if (s >= LOR_ - 1 && r == s - (LOR_ - 1))
            __builtin_nontemporal_store(hrv, out2 + (size_t)(b * R_ + r) * H_ + k);
        if (r == R_ - 1 && s >= R_ - 1)
            __builtin_nontemporal_store(hcv, out1 + (size_t)(b * LOR_ + (s - (R_ - 1))) * H_ + k);
    }
}

// ---------------------------------------------------------------------------
extern "C" void kernel_launch(void* const* d_in, const int* in_sizes, int n_in,
                              void* d_out, int out_size, void* d_ws, size_t ws_size,
                              hipStream_t stream) {
    const float* inp = (const float*)d_in[0];
    const float* W   = (const float*)d_in[1];
    const float* Bp  = (const float*)d_in[2];

    float* out0 = (float*)d_out;
    float* out1 = out0 + (size_t)N_ * L_ * 512;
    float* out2 = out1 + (size_t)32 * LOR_ * H_;

    char* ws = (char*)d_ws;
    _Float16* Wfrag = (_Float16*)(ws);                 // 1,671,168 B
    _Float16* xall  = (_Float16*)(ws + 1671168);       // 3,489,792 B
    _Float16* hb0   = (_Float16*)(ws + 5160960);       //   786,432 B
    _Float16* hb1   = (_Float16*)(ws + 5947392);       //   786,432 B (contiguous)

    prep_all<<<10848, 256, 0, stream>>>(W, inp, Wfrag, xall,
                                        (unsigned long long*)hb0);

    for (int s = 0; s < L_; ++s) {
        const _Float16* hbc = (s & 1) ? hb1 : hb0;
        _Float16*       hbn = (s & 1) ? hb0 : hb1;
        int act = (s < 23 ? s : 23) + 1;               // active r-groups
        int nmc = (32 * act + 47) / 48;                // active 48-row chunks
        step_k<<<nmc * 16, 768, 0, stream>>>(Wfrag, xall, hbc, hbn,
                                             Bp, out0, out1, out2, s);
    }
}